// Round 10
// baseline (657.568 us; speedup 1.0000x reference)
//
#include <hip/hip_runtime.h>
#include <hip/hip_fp16.h>

#define Hn 128
#define Wn 128
#define HWn 16384
#define Cn 64
#define Bn 8
#define NTOT (Bn*Cn*HWn)   /* 8388608 */
#define NPIX (Bn*HWn)      /* 131072  */
#define DTc 0.3f
#define EPSc 1e-5f

__device__ __forceinline__ float sigm(float t){ return 1.0f/(1.0f+__expf(-t)); }
__device__ __forceinline__ float2 uph(unsigned int u){
    __half2 h = *reinterpret_cast<__half2*>(&u); return __half22float2(h);
}
__device__ __forceinline__ unsigned int pkh(float a, float b){
    __half2 h = __floats2half2_rn(a, b); return *reinterpret_cast<unsigned int*>(&h);
}

// ---- pair-interleaved layout: elem (b,c,hw) -> uint index (b*32 + c/2)*HWn + hw, half (c&1)

// ---------------- F/XA/V producer: F=force+0.2*illum, x1=0.09F, v1=0.3F (pair layout) -----
__global__ void fuseF0(const float4* __restrict__ force, const float4* __restrict__ illum,
                       unsigned int* __restrict__ Fu, unsigned int* __restrict__ XAu,
                       unsigned int* __restrict__ Vu)
{
    int t = blockIdx.x * blockDim.x + threadIdx.x;     // [0, NTOT/8)
    int hw4 = t & 4095;                                // hw/4
    int cp  = (t >> 12) & 31;
    int b   = t >> 17;
    int r0 = (b*64 + 2*cp) * 4096 + hw4;               // float4 row indices
    int r1 = r0 + 4096;
    float4 fa = force[r0], fb = force[r1];
    float4 ia = illum[r0], ib = illum[r1];
    float A0 = fa.x + 0.2f*ia.x, A1 = fa.y + 0.2f*ia.y, A2 = fa.z + 0.2f*ia.z, A3 = fa.w + 0.2f*ia.w;
    float B0 = fb.x + 0.2f*ib.x, B1 = fb.y + 0.2f*ib.y, B2 = fb.z + 0.2f*ib.z, B3 = fb.w + 0.2f*ib.w;
    int u4 = ((b*32 + cp) * HWn >> 2) + hw4;           // uint4 index
    uint4 pf, px, pv;
    pf.x = pkh(A0,B0); pf.y = pkh(A1,B1); pf.z = pkh(A2,B2); pf.w = pkh(A3,B3);
    px.x = pkh(0.09f*A0,0.09f*B0); px.y = pkh(0.09f*A1,0.09f*B1);
    px.z = pkh(0.09f*A2,0.09f*B2); px.w = pkh(0.09f*A3,0.09f*B3);
    pv.x = pkh(0.3f*A0,0.3f*B0);   pv.y = pkh(0.3f*A1,0.3f*B1);
    pv.z = pkh(0.3f*A2,0.3f*B2);   pv.w = pkh(0.3f*A3,0.3f*B3);
    reinterpret_cast<uint4*>(Fu)[u4]  = pf;
    reinterpret_cast<uint4*>(XAu)[u4] = px;
    reinterpret_cast<uint4*>(Vu)[u4]  = pv;
}

// ---------------- prep: style constant + transposes + fp16 pair-packed osc weights -------
__global__ void prep(const float* __restrict__ style, const float* __restrict__ w1,
                     const float* __restrict__ b1, const float* __restrict__ pw,
                     const float* __restrict__ pw1, const float* __restrict__ pw2,
                     const float* __restrict__ dwk,
                     float* __restrict__ w1T, float* __restrict__ c1,
                     float* __restrict__ pw1T, float* __restrict__ pw2T,
                     __half2* __restrict__ pwP, __half2* __restrict__ dwkP)
{
    int t = threadIdx.x;
    if (t < 32) {
        float s = b1[t];
        for (int k = 0; k < 64; k++) s += w1[t*128 + 64 + k] * style[k];
        c1[t] = s;
    }
    for (int i = t; i < 2048; i += 256) { int c = i >> 5, j = i & 31; w1T[i] = w1[j*128 + c]; }
    for (int i = t; i < 4096; i += 256) {
        int c = i >> 6, k = i & 63;
        pw1T[i] = pw1[k*64 + c];
        pw2T[i] = pw2[k*64 + c];
    }
    // pwP[cp*64 + k] = (pw[k][2cp], pw[k][2cp+1])
    for (int i = t; i < 2048; i += 256) {
        int cp = i >> 6, k = i & 63;
        pwP[i] = __floats2half2_rn(pw[k*64 + 2*cp], pw[k*64 + 2*cp + 1]);
    }
    // dwkP[cp*9 + tap] = (dwk[2cp][tap], dwk[2cp+1][tap])
    for (int i = t; i < 288; i += 256) {
        int cp = i / 9, tp = i - cp*9;
        dwkP[i] = __floats2half2_rn(dwk[(2*cp)*9 + tp], dwk[(2*cp+1)*9 + tp]);
    }
}

// ---------------- hyper encoder: y=0 -> AB (pair layout), y=1 -> GB (linear half2) -------
__global__ void hyper2(const unsigned int* __restrict__ Fu,
                       const float* __restrict__ w1T, const float* __restrict__ c1,
                       const float* __restrict__ w2, const float* __restrict__ b2,
                       const float* __restrict__ w3, const float* __restrict__ b3,
                       uint2* __restrict__ ABu, __half2* __restrict__ GB)
{
    int p = blockIdx.x * blockDim.x + threadIdx.x;
    int b  = p >> 14;
    int sp = p & (HWn - 1);
    int pbase = b * 32 * HWn + sp;                 // uint pair-row base
    int gbase = b * Cn * HWn + sp;                 // linear base (GB)

    float u1[32];
#pragma unroll
    for (int j = 0; j < 32; j++) u1[j] = c1[j];
#pragma unroll 4
    for (int cp = 0; cp < 32; cp++) {
        float2 fc = uph(Fu[pbase + cp*HWn]);
        const float* __restrict__ w0 = w1T + (2*cp)*32;
        const float* __restrict__ w1r = w0 + 32;
#pragma unroll
        for (int j = 0; j < 32; j++) u1[j] += w0[j]*fc.x + w1r[j]*fc.y;
    }
#pragma unroll
    for (int j = 0; j < 32; j++) { float v = u1[j]; u1[j] = v > 0.f ? v : 0.2f*v; }

    float u2[32];
#pragma unroll
    for (int i = 0; i < 32; i++) {
        float s = b2[i];
#pragma unroll
        for (int j = 0; j < 32; j++) s += w2[i*32 + j] * u1[j];
        u2[i] = s > 0.f ? s : 0.2f*s;
    }

    if (blockIdx.y == 0) {
        for (int jp = 0; jp < 32; jp++) {
            int j0 = 2*jp, j1 = 2*jp + 1;
            const float* __restrict__ rw0 = w3 + j0*32;
            const float* __restrict__ rw1 = w3 + j1*32;
            const float* __restrict__ rz0 = w3 + (64 + j0)*32;
            const float* __restrict__ rz1 = w3 + (64 + j1)*32;
            float pw0 = b3[j0], pw1v = b3[j1], pz0 = b3[64+j0], pz1 = b3[64+j1];
#pragma unroll
            for (int i = 0; i < 32; i++) {
                float u = u2[i];
                pw0 += rw0[i]*u; pw1v += rw1[i]*u; pz0 += rz0[i]*u; pz1 += rz1[i]*u;
            }
            float om0 = 2.0f*sigm(pw0), om1 = 2.0f*sigm(pw1v);
            float ze0 = sigm(pz0),      ze1 = sigm(pz1);
            uint2 o;
            o.x = pkh(2.0f*ze0*om0, om0*om0);
            o.y = pkh(2.0f*ze1*om1, om1*om1);
            ABu[pbase + jp*HWn] = o;
        }
    } else {
        for (int j = 0; j < 64; j++) {
            const float* __restrict__ r2 = w3 + (128 + j)*32;
            const float* __restrict__ r3 = w3 + (192 + j)*32;
            float pg = b3[128 + j], pb = b3[192 + j];
#pragma unroll
            for (int i = 0; i < 32; i++) { pg += r2[i]*u2[i]; pb += r3[i]*u2[i]; }
            GB[gbase + j*HWn] = __floats2half2_rn(2.0f * sigm(pg), tanhf(pb));
        }
    }
}

// ---------------- oscillator step: 2 px x 8 ch (4 pairs)/thread, fp16 packed weights -----
template <bool LAST>
__global__ __launch_bounds__(256)
void osc_step(const unsigned int* __restrict__ Xin, unsigned int* __restrict__ Xout,
              unsigned int* __restrict__ V, const unsigned int* __restrict__ F,
              const uint2* __restrict__ AB,
              const __half2* __restrict__ dwkP, const uint4* __restrict__ pwPq,
              float* __restrict__ Xf, float* __restrict__ Vf)
{
    int q  = blockIdx.x * blockDim.x + threadIdx.x;    // pixel-pair id [0, NPIX/2)
    int gy = blockIdx.y;                               // 0..7 : 8-channel group
    int p0 = q << 1;
    int b  = p0 >> 14;
    int sp = p0 & (HWn - 1);
    int y = sp >> 7, x0 = sp & 127;                    // x0 even
    int pbase = b * 32 * HWn + sp;

    // pointwise coupling: acc{0,1}[j] = sum_c pw[8gy+j][c]*x[c] at px0/px1
    float acc0[8], acc1[8];
#pragma unroll
    for (int j = 0; j < 8; j++) { acc0[j] = 0.f; acc1[j] = 0.f; }
#pragma unroll 4
    for (int cp = 0; cp < 32; cp++) {
        uint2 xu = *reinterpret_cast<const uint2*>(Xin + pbase + cp*HWn);
        float2 xa = uph(xu.x), xb = uph(xu.y);
        uint4 wA = pwPq[cp*16 + (gy << 1)];
        uint4 wB = pwPq[cp*16 + (gy << 1) + 1];
        float2 w;
        w = uph(wA.x); acc0[0] += w.x*xa.x + w.y*xa.y; acc1[0] += w.x*xb.x + w.y*xb.y;
        w = uph(wA.y); acc0[1] += w.x*xa.x + w.y*xa.y; acc1[1] += w.x*xb.x + w.y*xb.y;
        w = uph(wA.z); acc0[2] += w.x*xa.x + w.y*xa.y; acc1[2] += w.x*xb.x + w.y*xb.y;
        w = uph(wA.w); acc0[3] += w.x*xa.x + w.y*xa.y; acc1[3] += w.x*xb.x + w.y*xb.y;
        w = uph(wB.x); acc0[4] += w.x*xa.x + w.y*xa.y; acc1[4] += w.x*xb.x + w.y*xb.y;
        w = uph(wB.y); acc0[5] += w.x*xa.x + w.y*xa.y; acc1[5] += w.x*xb.x + w.y*xb.y;
        w = uph(wB.z); acc0[6] += w.x*xa.x + w.y*xa.y; acc1[6] += w.x*xb.x + w.y*xb.y;
        w = uph(wB.w); acc0[7] += w.x*xa.x + w.y*xa.y; acc1[7] += w.x*xb.x + w.y*xb.y;
    }

    int   yo[3] = { y > 0 ? -Wn : 0, 0, y < Hn-1 ? Wn : 0 };
    float my[3] = { y > 0 ? 1.f : 0.f, 1.f, y < Hn-1 ? 1.f : 0.f };
    float wl = x0 > 0   ? 1.f : 0.f;                   // px0 left tap valid
    float wr = x0 < 126 ? 1.f : 0.f;                   // px1 right tap valid

#pragma unroll
    for (int pp = 0; pp < 4; pp++) {
        int cp = (gy << 2) + pp;
        int c  = cp << 1;
        int ub = pbase + cp*HWn;
        float2 ct0[3], ct1[3], lf[3], rt[3];           // (ch a, ch b) values
#pragma unroll
        for (int r = 0; r < 3; r++) {
            int rb = ub + yo[r];
            uint2 cu = *reinterpret_cast<const uint2*>(Xin + rb);
            unsigned int lu = Xin[rb - 1];             // masked by wl; OOB-by-1 stays in ws
            unsigned int ru = Xin[rb + 2];             // masked by wr
            ct0[r] = uph(cu.x); ct1[r] = uph(cu.y);
            lf[r]  = uph(lu);   rt[r]  = uph(ru);
        }
        float d0a = 0.f, d0b = 0.f, d1a = 0.f, d1b = 0.f;
#pragma unroll
        for (int r = 0; r < 3; r++) {
            float2 k0 = uph(*(const unsigned int*)&dwkP[cp*9 + r*3 + 0]);
            float2 k1 = uph(*(const unsigned int*)&dwkP[cp*9 + r*3 + 1]);
            float2 k2 = uph(*(const unsigned int*)&dwkP[cp*9 + r*3 + 2]);
            float m = my[r];
            k0.x *= m; k0.y *= m; k1.x *= m; k1.y *= m; k2.x *= m; k2.y *= m;
            d0a += k0.x*(wl*lf[r].x) + k1.x*ct0[r].x + k2.x*ct1[r].x;
            d0b += k0.y*(wl*lf[r].y) + k1.y*ct0[r].y + k2.y*ct1[r].y;
            d1a += k0.x*ct0[r].x + k1.x*ct1[r].x + k2.x*(wr*rt[r].x);
            d1b += k0.y*ct0[r].y + k1.y*ct1[r].y + k2.y*(wr*rt[r].y);
        }
        uint2 vu = *reinterpret_cast<const uint2*>(V + ub);
        uint2 fu = *reinterpret_cast<const uint2*>(F + ub);
        uint4 abu = *reinterpret_cast<const uint4*>(AB + ub);
        float2 v0p = uph(vu.x), v1p = uph(vu.y);
        float2 f0p = uph(fu.x), f1p = uph(fu.y);
        float2 ab0a = uph(abu.x), ab0b = uph(abu.y);   // px0: (A,B2) ch a / ch b
        float2 ab1a = uph(abu.z), ab1b = uph(abu.w);   // px1
        float x0a = ct0[1].x, x0b = ct0[1].y, x1a = ct1[1].x, x1b = ct1[1].y;
        float ac0a = f0p.x + acc0[2*pp]   + d0a - ab0a.x*v0p.x - ab0a.y*x0a;
        float ac0b = f0p.y + acc0[2*pp+1] + d0b - ab0b.x*v0p.y - ab0b.y*x0b;
        float ac1a = f1p.x + acc1[2*pp]   + d1a - ab1a.x*v1p.x - ab1a.y*x1a;
        float ac1b = f1p.y + acc1[2*pp+1] + d1b - ab1b.x*v1p.y - ab1b.y*x1b;
        float nv0a = v0p.x + ac0a*DTc, nv0b = v0p.y + ac0b*DTc;
        float nv1a = v1p.x + ac1a*DTc, nv1b = v1p.y + ac1b*DTc;
        float nx0a = x0a + nv0a*DTc, nx0b = x0b + nv0b*DTc;
        float nx1a = x1a + nv1a*DTc, nx1b = x1b + nv1b*DTc;
        if constexpr (!LAST) {
            uint2 vo, xo2;
            vo.x  = pkh(nv0a, nv0b); vo.y  = pkh(nv1a, nv1b);
            xo2.x = pkh(nx0a, nx0b); xo2.y = pkh(nx1a, nx1b);
            *reinterpret_cast<uint2*>(V + ub)    = vo;
            *reinterpret_cast<uint2*>(Xout + ub) = xo2;
        } else {
            int lb = (b*64 + c)*HWn + sp;              // linear fp32, ch a px0
            *reinterpret_cast<float2*>(Xf + lb)       = make_float2(nx0a, nx1a);
            *reinterpret_cast<float2*>(Xf + lb + HWn) = make_float2(nx0b, nx1b);
            *reinterpret_cast<float2*>(Vf + lb)       = make_float2(nv0a, nv1a);
            *reinterpret_cast<float2*>(Vf + lb + HWn) = make_float2(nv0b, nv1b);
        }
    }
}

// ---------------- instance norm stats: one block per channel PAIR ----------------
__global__ void inorm_stats(const unsigned int* __restrict__ Fu, const float* __restrict__ X,
                            float* __restrict__ mu, float* __restrict__ rs)
{
    int bp = blockIdx.x;             // 0..255 : (b*32 + cp)
    int ub = bp * HWn;
    const uint4*  __restrict__ F4 = (const uint4*)(Fu + ub);
    const float4* __restrict__ X0 = (const float4*)(X + 2*(size_t)ub);
    const float4* __restrict__ X1 = X0 + HWn/4;
    float s0 = 0.f, q0 = 0.f, s1 = 0.f, q1 = 0.f;
    for (int i = threadIdx.x; i < HWn/4; i += blockDim.x) {
        uint4 fd = F4[i];
        float4 xa = X0[i], xb = X1[i];
        float2 f0 = uph(fd.x), f1 = uph(fd.y), f2 = uph(fd.z), f3 = uph(fd.w);
        float a0 = f0.x + xa.x, a1 = f1.x + xa.y, a2 = f2.x + xa.z, a3 = f3.x + xa.w;
        float b0 = f0.y + xb.x, b1 = f1.y + xb.y, b2 = f2.y + xb.z, b3 = f3.y + xb.w;
        s0 += (a0 + a1) + (a2 + a3);
        q0 += (a0*a0 + a1*a1) + (a2*a2 + a3*a3);
        s1 += (b0 + b1) + (b2 + b3);
        q1 += (b0*b0 + b1*b1) + (b2*b2 + b3*b3);
    }
#pragma unroll
    for (int o = 32; o > 0; o >>= 1) {
        s0 += __shfl_down(s0, o); q0 += __shfl_down(q0, o);
        s1 += __shfl_down(s1, o); q1 += __shfl_down(q1, o);
    }
    __shared__ float sh[32];
    int w = threadIdx.x >> 6, l = threadIdx.x & 63;
    if (l == 0) { sh[w] = s0; sh[8+w] = q0; sh[16+w] = s1; sh[24+w] = q1; }
    __syncthreads();
    if (threadIdx.x == 0) {
        float S0=0.f, Q0=0.f, S1=0.f, Q1=0.f;
        for (int i = 0; i < 4; i++) { S0+=sh[i]; Q0+=sh[8+i]; S1+=sh[16+i]; Q1+=sh[24+i]; }
        float m0 = S0/(float)HWn, m1 = S1/(float)HWn;
        mu[2*bp]   = m0;  rs[2*bp]   = rsqrtf(Q0/(float)HWn - m0*m0 + EPSc);
        mu[2*bp+1] = m1;  rs[2*bp+1] = rsqrtf(Q1/(float)HWn - m1*m1 + EPSc);
    }
}

// ---------------- instance norm apply + style modulation -> outp (linear fp16) ----------
__global__ void modulate(const unsigned int* __restrict__ Fu, const float* __restrict__ X,
                         const unsigned int* __restrict__ GBu, const float* __restrict__ mu,
                         const float* __restrict__ rs, __half* __restrict__ outp)
{
    int t = blockIdx.x * blockDim.x + threadIdx.x;     // [0, NTOT/8)
    int hw4 = t & 4095;
    int cp  = (t >> 12) & 31;
    int b   = t >> 17;
    int c0 = 2*cp;
    int bc0 = b*64 + c0;
    float m0 = mu[bc0], r0 = rs[bc0], m1 = mu[bc0+1], r1 = rs[bc0+1];
    uint4 fd = reinterpret_cast<const uint4*>(Fu)[((b*32 + cp)*HWn >> 2) + hw4];
    int l0 = (bc0*HWn >> 2) + hw4;
    float4 xa = reinterpret_cast<const float4*>(X)[l0];
    float4 xb = reinterpret_cast<const float4*>(X)[l0 + 4096];
    uint4 ga = reinterpret_cast<const uint4*>(GBu)[l0];
    uint4 gb = reinterpret_cast<const uint4*>(GBu)[l0 + 4096];
    float2 f0 = uph(fd.x), f1 = uph(fd.y), f2 = uph(fd.z), f3 = uph(fd.w);
    float2 g0 = uph(ga.x), g1 = uph(ga.y), g2 = uph(ga.z), g3 = uph(ga.w);
    float2 h0 = uph(gb.x), h1 = uph(gb.y), h2 = uph(gb.z), h3 = uph(gb.w);
    float oa0 = g0.x * ((f0.x + xa.x - m0) * r0) + g0.y;
    float oa1 = g1.x * ((f1.x + xa.y - m0) * r0) + g1.y;
    float oa2 = g2.x * ((f2.x + xa.z - m0) * r0) + g2.y;
    float oa3 = g3.x * ((f3.x + xa.w - m0) * r0) + g3.y;
    float ob0 = h0.x * ((f0.y + xb.x - m1) * r1) + h0.y;
    float ob1 = h1.x * ((f1.y + xb.y - m1) * r1) + h1.y;
    float ob2 = h2.x * ((f2.y + xb.z - m1) * r1) + h2.y;
    float ob3 = h3.x * ((f3.y + xb.w - m1) * r1) + h3.y;
    uint2 pa, pb;
    pa.x = pkh(oa0, oa1); pa.y = pkh(oa2, oa3);
    pb.x = pkh(ob0, ob1); pb.y = pkh(ob2, ob3);
    int hw0 = hw4 << 2;
    *reinterpret_cast<uint2*>(outp + (size_t)bc0*HWn + hw0)     = pa;
    *reinterpret_cast<uint2*>(outp + (size_t)(bc0+1)*HWn + hw0) = pb;
}

// ---------------- refine: LDS weights + packed fp16 hfma2 phases 2/3 (unchanged) --------
__global__ __launch_bounds__(512)
void refine(const __half* __restrict__ outp,
            const float* __restrict__ rdwk, const float* __restrict__ rdwb,
            const float* __restrict__ pw1T, const float* __restrict__ pb1,
            const float* __restrict__ pw2T, const float* __restrict__ pb2,
            const float* __restrict__ ls, float* __restrict__ out)
{
    __shared__ __half rv_s[64][128];
    __shared__ __half act_s[64][128];
    __shared__ __half w1s[64][64];
    __shared__ __half w2s[64][64];
    __shared__ float  dwks[576];
    __shared__ __half2 pb1h[32], pb2h[32];
    __shared__ float  rdwbs[64], lss[64];
    int t = threadIdx.x;
    for (int i = t; i < 4096; i += 512) {
        w1s[i>>6][i&63] = __float2half(pw1T[i]);
        w2s[i>>6][i&63] = __float2half(pw2T[i]);
    }
    for (int i = t; i < 576; i += 512) dwks[i] = rdwk[i];
    if (t < 64) { rdwbs[t]=rdwb[t]; lss[t]=ls[t]; }
    if (t < 32) {
        pb1h[t] = __floats2half2_rn(pb1[2*t], pb1[2*t+1]);
        pb2h[t] = __floats2half2_rn(pb2[2*t], pb2[2*t+1]);
    }

    int l = t & 127;
    int w = t >> 7;
    int c0 = w << 4;
    int p = blockIdx.x * 128 + l;
    int b  = p >> 14;
    int sp = p & (HWn - 1);
    int y = sp >> 7, x = sp & 127;
    int base = b * Cn * HWn + sp;

    int   yo[3] = { y > 0 ? -Wn : 0, 0, y < Hn-1 ? Wn : 0 };
    int   xo[3] = { x > 0 ? -1  : 0, 0, x < Wn-1 ? 1  : 0 };
    float myv[3] = { y > 0 ? 1.f : 0.f, 1.f, y < Hn-1 ? 1.f : 0.f };
    float mxv[3] = { x > 0 ? 1.f : 0.f, 1.f, x < Wn-1 ? 1.f : 0.f };
    float mm[9]; int oo[9];
#pragma unroll
    for (int dy = 0; dy < 3; dy++)
#pragma unroll
        for (int dx = 0; dx < 3; dx++) { mm[dy*3+dx] = myv[dy]*mxv[dx]; oo[dy*3+dx] = yo[dy]+xo[dx]; }
    __syncthreads();

#pragma unroll
    for (int cc = 0; cc < 16; cc++) {
        int c = c0 + cc;
        int cb = base + c*HWn;
        float rv = rdwbs[c];
#pragma unroll
        for (int tt = 0; tt < 9; tt++)
            rv += (dwks[c*9 + tt] * mm[tt]) * __half2float(outp[cb + oo[tt]]);
        rv_s[c][l] = __float2half(rv);
    }
    __syncthreads();

    __half2 acc2[8];
#pragma unroll
    for (int q = 0; q < 8; q++) acc2[q] = pb1h[(c0 >> 1) + q];
#pragma unroll 4
    for (int c = 0; c < 64; c++) {
        __half2 rvh = __half2half2(rv_s[c][l]);
        const __half2* wrow = (const __half2*)&w1s[c][c0];
#pragma unroll
        for (int q = 0; q < 8; q++) acc2[q] = __hfma2(wrow[q], rvh, acc2[q]);
    }
#pragma unroll
    for (int q = 0; q < 8; q++) {
        float2 a = __half22float2(acc2[q]);
        float a0 = a.x > 0.f ? a.x : 0.2f*a.x;
        float a1 = a.y > 0.f ? a.y : 0.2f*a.y;
        act_s[c0 + 2*q][l]     = __float2half(a0);
        act_s[c0 + 2*q + 1][l] = __float2half(a1);
    }
    __syncthreads();

#pragma unroll
    for (int q = 0; q < 8; q++) acc2[q] = pb2h[(c0 >> 1) + q];
#pragma unroll 4
    for (int j = 0; j < 64; j++) {
        __half2 ah = __half2half2(act_s[j][l]);
        const __half2* wrow = (const __half2*)&w2s[j][c0];
#pragma unroll
        for (int q = 0; q < 8; q++) acc2[q] = __hfma2(wrow[q], ah, acc2[q]);
    }
#pragma unroll
    for (int q = 0; q < 8; q++) {
        float2 r = __half22float2(acc2[q]);
        int ca = c0 + 2*q, cb2 = c0 + 2*q + 1;
        int ba = base + ca*HWn, bb = base + cb2*HWn;
        out[ba] = __half2float(outp[ba]) + lss[ca] * r.x;
        out[bb] = __half2float(outp[bb]) + lss[cb2] * r.y;
    }
}

extern "C" void kernel_launch(void* const* d_in, const int* in_sizes, int n_in,
                              void* d_out, int out_size, void* d_ws, size_t ws_size,
                              hipStream_t stream)
{
    (void)in_sizes; (void)n_in; (void)out_size; (void)ws_size;
    const float* force   = (const float*)d_in[0];
    const float* style   = (const float*)d_in[1];
    const float* illum   = (const float*)d_in[2];
    const float* h_w1    = (const float*)d_in[3];
    const float* h_b1    = (const float*)d_in[4];
    const float* h_w2    = (const float*)d_in[5];
    const float* h_b2    = (const float*)d_in[6];
    const float* h_w3    = (const float*)d_in[7];
    const float* h_b3    = (const float*)d_in[8];
    const float* dw_k    = (const float*)d_in[9];
    const float* pw_w    = (const float*)d_in[10];
    const float* r_dw_k  = (const float*)d_in[11];
    const float* r_dw_b  = (const float*)d_in[12];
    const float* r_pw1_w = (const float*)d_in[13];
    const float* r_pw1_b = (const float*)d_in[14];
    const float* r_pw2_w = (const float*)d_in[15];
    const float* r_pw2_b = (const float*)d_in[16];
    const float* lscale  = (const float*)d_in[17];

    float* out  = (float*)d_out;              // holds GB (half2) until refine overwrites
    float* Xf32 = out + (size_t)NTOT;         // final x fp32
    float* Vf32 = out + 2*(size_t)NTOT;       // final v fp32
    unsigned int* GBu = (unsigned int*)out;

    char* w = (char*)d_ws;
    uint2*        ABu = (uint2*)w;        w += (size_t)NTOT*4;   // pair layout
    unsigned int* Fu  = (unsigned int*)w; w += (size_t)NTOT*2;
    unsigned int* XAu = (unsigned int*)w; w += (size_t)NTOT*2;
    unsigned int* XBu = (unsigned int*)w; w += (size_t)NTOT*2;
    unsigned int* Vu  = (unsigned int*)w; w += (size_t)NTOT*2;
    __half2* pwP  = (__half2*)w;          w += 2048*4;           // 16B-aligned
    __half2* dwkP = (__half2*)w;          w += 288*4;
    float* w1T  = (float*)w;
    float* c1   = w1T + 2048;
    float* pw1T = c1 + 32;
    float* pw2T = pw1T + 4096;
    float* mu   = pw2T + 4096;
    float* rs   = mu + 512;
    __half* outp = (__half*)ABu;              // AB dead after last osc step

    fuseF0<<<NTOT/2048, 256, 0, stream>>>((const float4*)force, (const float4*)illum,
                                          Fu, XAu, Vu);
    prep<<<1, 256, 0, stream>>>(style, h_w1, h_b1, pw_w, r_pw1_w, r_pw2_w, dw_k,
                                w1T, c1, pw1T, pw2T, pwP, dwkP);
    hyper2<<<dim3(NPIX/256, 2), 256, 0, stream>>>(Fu, w1T, c1, h_w2, h_b2, h_w3, h_b3,
                                                  ABu, (__half2*)GBu);
    for (int s = 1; s <= 8; s++) {
        const unsigned int* xin = (s & 1) ? XAu : XBu;
        unsigned int*      xout = (s & 1) ? XBu : XAu;
        osc_step<false><<<dim3(NPIX/512, 8), 256, 0, stream>>>(xin, xout, Vu, Fu, ABu,
                                                               dwkP, (const uint4*)pwP,
                                                               nullptr, nullptr);
    }
    // step 9 (odd): reads XAu, writes fp32 x,v directly to d_out (linear)
    osc_step<true><<<dim3(NPIX/512, 8), 256, 0, stream>>>(XAu, XBu, Vu, Fu, ABu,
                                                          dwkP, (const uint4*)pwP,
                                                          Xf32, Vf32);
    inorm_stats<<<Bn*32, 256, 0, stream>>>(Fu, Xf32, mu, rs);
    modulate<<<NTOT/2048, 256, 0, stream>>>(Fu, Xf32, GBu, mu, rs, outp);
    refine<<<NPIX/128, 512, 0, stream>>>(outp, r_dw_k, r_dw_b, pw1T, r_pw1_b,
                                         pw2T, r_pw2_b, lscale, out);
}

// Round 11
// 508.738 us; speedup vs baseline: 1.2925x; 1.2925x over previous
//
#include <hip/hip_runtime.h>
#include <hip/hip_fp16.h>

#define Hn 128
#define Wn 128
#define HWn 16384
#define Cn 64
#define Bn 8
#define NTOT (Bn*Cn*HWn)   /* 8388608 */
#define NPIX (Bn*HWn)      /* 131072  */
#define DTc 0.3f
#define EPSc 1e-5f

__device__ __forceinline__ float sigm(float t){ return 1.0f/(1.0f+__expf(-t)); }

// ---------------- F = force + 0.2*illum (fp16) + fused oscillator step 0 ----------------
// x0=v0=0  =>  accel0 = F, v1 = 0.3*F, x1 = 0.09*F
__global__ void fuseF0(const float4* __restrict__ force, const float4* __restrict__ illum,
                       __half* __restrict__ F, __half* __restrict__ XA, __half* __restrict__ V)
{
    int i = blockIdx.x * blockDim.x + threadIdx.x;      // NTOT/4 threads
    float4 f = force[i], il = illum[i];
    float a0 = f.x + 0.2f*il.x, a1 = f.y + 0.2f*il.y;
    float a2 = f.z + 0.2f*il.z, a3 = f.w + 0.2f*il.w;
    uint2 pf, px, pv;
    __half2 h;
    h = __floats2half2_rn(a0, a1);            pf.x = *(unsigned int*)&h;
    h = __floats2half2_rn(a2, a3);            pf.y = *(unsigned int*)&h;
    h = __floats2half2_rn(0.09f*a0, 0.09f*a1); px.x = *(unsigned int*)&h;
    h = __floats2half2_rn(0.09f*a2, 0.09f*a3); px.y = *(unsigned int*)&h;
    h = __floats2half2_rn(0.3f*a0, 0.3f*a1);   pv.x = *(unsigned int*)&h;
    h = __floats2half2_rn(0.3f*a2, 0.3f*a3);   pv.y = *(unsigned int*)&h;
    *reinterpret_cast<uint2*>(F  + 4*(size_t)i) = pf;
    *reinterpret_cast<uint2*>(XA + 4*(size_t)i) = px;
    *reinterpret_cast<uint2*>(V  + 4*(size_t)i) = pv;
}

// ---------------- prep: style constant + weight transposes ----------------
__global__ void prep(const float* __restrict__ style, const float* __restrict__ w1,
                     const float* __restrict__ b1, const float* __restrict__ pw,
                     const float* __restrict__ pw1, const float* __restrict__ pw2,
                     float* __restrict__ w1T, float* __restrict__ c1,
                     float* __restrict__ pwT, float* __restrict__ pw1T,
                     float* __restrict__ pw2T)
{
    int t = threadIdx.x;
    if (t < 32) {
        float s = b1[t];
        for (int k = 0; k < 64; k++) s += w1[t*128 + 64 + k] * style[k];
        c1[t] = s;
    }
    for (int i = t; i < 2048; i += 256) { int c = i >> 5, j = i & 31; w1T[i] = w1[j*128 + c]; }
    for (int i = t; i < 4096; i += 256) {
        int c = i >> 6, k = i & 63;
        pwT[i]  = pw[k*64 + c];
        pw1T[i] = pw1[k*64 + c];
        pw2T[i] = pw2[k*64 + c];
    }
}

// ---------------- hyper encoder, 2-way split: y=0 -> AB(half2), y=1 -> GB(half2) --------
__global__ void hyper2(const __half* __restrict__ F,
                       const float* __restrict__ w1T, const float* __restrict__ c1,
                       const float* __restrict__ w2, const float* __restrict__ b2,
                       const float* __restrict__ w3, const float* __restrict__ b3,
                       __half2* __restrict__ AB, __half2* __restrict__ GB)
{
    int p = blockIdx.x * blockDim.x + threadIdx.x;
    int b  = p >> 14;
    int sp = p & (HWn - 1);
    int base = b * Cn * HWn + sp;

    float u1[32];
#pragma unroll
    for (int j = 0; j < 32; j++) u1[j] = c1[j];
#pragma unroll 4
    for (int c = 0; c < 64; c++) {
        float fc = __half2float(F[base + c*HWn]);
        const float* __restrict__ wr = w1T + c*32;
#pragma unroll
        for (int j = 0; j < 32; j++) u1[j] += wr[j] * fc;
    }
#pragma unroll
    for (int j = 0; j < 32; j++) { float v = u1[j]; u1[j] = v > 0.f ? v : 0.2f*v; }

    float u2[32];
#pragma unroll
    for (int i = 0; i < 32; i++) {
        float s = b2[i];
#pragma unroll
        for (int j = 0; j < 32; j++) s += w2[i*32 + j] * u1[j];
        u2[i] = s > 0.f ? s : 0.2f*s;
    }

    if (blockIdx.y == 0) {
        for (int j = 0; j < 64; j++) {
            const float* __restrict__ r0 = w3 + j*32;
            const float* __restrict__ r1 = w3 + (64 + j)*32;
            float pwv = b3[j], pz = b3[64 + j];
#pragma unroll
            for (int i = 0; i < 32; i++) { pwv += r0[i]*u2[i]; pz += r1[i]*u2[i]; }
            float om = 2.0f * sigm(pwv);
            float ze = sigm(pz);
            AB[base + j*HWn] = __floats2half2_rn(2.0f * ze * om, om * om);
        }
    } else {
        for (int j = 0; j < 64; j++) {
            const float* __restrict__ r2 = w3 + (128 + j)*32;
            const float* __restrict__ r3 = w3 + (192 + j)*32;
            float pg = b3[128 + j], pb = b3[192 + j];
#pragma unroll
            for (int i = 0; i < 32; i++) { pg += r2[i]*u2[i]; pb += r3[i]*u2[i]; }
            GB[base + j*HWn] = __floats2half2_rn(2.0f * sigm(pg), tanhf(pb));
        }
    }
}

// ---------------- one symplectic-Euler oscillator step (R8-proven structure) ------------
template <bool LAST>
__global__ void osc_step(const __half* __restrict__ Xin, __half* __restrict__ Xout,
                         __half* __restrict__ V, const __half* __restrict__ F,
                         const __half2* __restrict__ AB,
                         const float* __restrict__ dwk, const float* __restrict__ pwT,
                         float* __restrict__ Xf, float* __restrict__ Vf)
{
    int p = blockIdx.x * blockDim.x + threadIdx.x;
    int c0 = blockIdx.y << 4;                 // channel group start
    int b  = p >> 14;
    int sp = p & (HWn - 1);
    int y = sp >> 7, x = sp & 127;
    int base = b * Cn * HWn + sp;

    // pointwise coupling: acc[kk] = sum_c pw[c0+kk][c] * x[c]
    float acc[16];
#pragma unroll
    for (int k = 0; k < 16; k++) acc[k] = 0.f;
#pragma unroll 4
    for (int c = 0; c < 64; c++) {
        float xc = __half2float(Xin[base + c*HWn]);
        const float* __restrict__ wr = pwT + c*64 + c0;
#pragma unroll
        for (int k = 0; k < 16; k++) acc[k] += wr[k] * xc;
    }

    // 3x3 tap masks/offsets (zero 'SAME' padding)
    int   yo[3] = { y > 0 ? -Wn : 0, 0, y < Hn-1 ? Wn : 0 };
    int   xo[3] = { x > 0 ? -1  : 0, 0, x < Wn-1 ? 1  : 0 };
    float my[3] = { y > 0 ? 1.f : 0.f, 1.f, y < Hn-1 ? 1.f : 0.f };
    float mx[3] = { x > 0 ? 1.f : 0.f, 1.f, x < Wn-1 ? 1.f : 0.f };
    float mm[9]; int oo[9];
#pragma unroll
    for (int dy = 0; dy < 3; dy++)
#pragma unroll
        for (int dx = 0; dx < 3; dx++) { mm[dy*3+dx] = my[dy]*mx[dx]; oo[dy*3+dx] = yo[dy]+xo[dx]; }

#pragma unroll
    for (int cc = 0; cc < 16; cc++) {
        int c = c0 + cc;
        int cb = base + c*HWn;
        float tv[9];
#pragma unroll
        for (int t = 0; t < 9; t++) tv[t] = __half2float(Xin[cb + oo[t]]);
        float dws = 0.f;
#pragma unroll
        for (int t = 0; t < 9; t++) dws += (dwk[c*9 + t] * mm[t]) * tv[t];
        float xc = tv[4];
        float2 ab = __half22float2(AB[cb]);
        float vv = __half2float(V[cb]);
        float accel = __half2float(F[cb]) + acc[cc] + dws - ab.x * vv - ab.y * xc;
        vv += accel * DTc;
        float xn = xc + vv * DTc;
        if constexpr (!LAST) {
            V[cb] = __float2half(vv);
            Xout[cb] = __float2half(xn);
        } else {
            Xf[cb] = xn;
            Vf[cb] = vv;
        }
    }
}

// ---------------- instance norm stats ----------------
__global__ void inorm_stats(const __half* __restrict__ F, const float* __restrict__ X,
                            float* __restrict__ mu, float* __restrict__ rs)
{
    int bc = blockIdx.x;             // 0..511
    int base = bc * HWn;
    const __half2* __restrict__ F2 = (const __half2*)(F + base);
    const float4*  __restrict__ X4 = (const float4*)(X + base);
    float s = 0.f, s2 = 0.f;
    for (int i = threadIdx.x; i < HWn/4; i += blockDim.x) {
        float4 xv = X4[i];
        float2 f0 = __half22float2(F2[2*i]);
        float2 f1 = __half22float2(F2[2*i+1]);
        float v0 = f0.x + xv.x, v1 = f0.y + xv.y, v2 = f1.x + xv.z, v3 = f1.y + xv.w;
        s += (v0 + v1) + (v2 + v3);
        s2 += (v0*v0 + v1*v1) + (v2*v2 + v3*v3);
    }
#pragma unroll
    for (int o = 32; o > 0; o >>= 1) { s += __shfl_down(s, o); s2 += __shfl_down(s2, o); }
    __shared__ float sh[16];
    int w = threadIdx.x >> 6, l = threadIdx.x & 63;
    if (l == 0) { sh[w] = s; sh[8 + w] = s2; }
    __syncthreads();
    if (threadIdx.x == 0) {
        float S = 0.f, S2 = 0.f;
        for (int i = 0; i < 4; i++) { S += sh[i]; S2 += sh[8 + i]; }
        float m = S / (float)HWn;
        float var = S2 / (float)HWn - m*m;
        mu[bc] = m;
        rs[bc] = rsqrtf(var + EPSc);
    }
}

// ---------------- instance norm apply + style modulation -> out_pre (fp16) ----------------
__global__ void modulate(const __half* __restrict__ F, const float4* __restrict__ X4,
                         const uint4* __restrict__ GBu, const float* __restrict__ mu,
                         const float* __restrict__ rs, __half* __restrict__ outp)
{
    int e4 = blockIdx.x * blockDim.x + threadIdx.x;   // NTOT/4 threads
    int bc = e4 >> 12;                                // (e4*4) >> 14
    float m = mu[bc], r = rs[bc];
    uint2 fu = *reinterpret_cast<const uint2*>(F + 4*(size_t)e4);
    float2 f0 = __half22float2(*(__half2*)&fu.x);
    float2 f1 = __half22float2(*(__half2*)&fu.y);
    float4 xv = X4[e4];
    uint4 gb = GBu[e4];
    float2 g0 = __half22float2(*(__half2*)&gb.x);
    float2 g1 = __half22float2(*(__half2*)&gb.y);
    float2 g2 = __half22float2(*(__half2*)&gb.z);
    float2 g3 = __half22float2(*(__half2*)&gb.w);
    float o0 = g0.x * ((f0.x + xv.x - m) * r) + g0.y;
    float o1 = g1.x * ((f0.y + xv.y - m) * r) + g1.y;
    float o2 = g2.x * ((f1.x + xv.z - m) * r) + g2.y;
    float o3 = g3.x * ((f1.y + xv.w - m) * r) + g3.y;
    __half2 h01 = __floats2half2_rn(o0, o1);
    __half2 h23 = __floats2half2_rn(o2, o3);
    uint2 pack; pack.x = *(unsigned int*)&h01; pack.y = *(unsigned int*)&h23;
    *reinterpret_cast<uint2*>(outp + 4*(size_t)e4) = pack;
}

// ---------------- refine v3: one row/block, 2 px x 8 ch per thread, b128 weight reads ----
// 512 threads: l = t&63 (px-pair), g = t>>6 (0..7), c0 = 8g. Row = blockIdx.x.
__global__ __launch_bounds__(512)
void refine(const __half* __restrict__ outp,
            const float* __restrict__ rdwk, const float* __restrict__ rdwb,
            const float* __restrict__ pw1T, const float* __restrict__ pb1,
            const float* __restrict__ pw2T, const float* __restrict__ pb2,
            const float* __restrict__ ls, float* __restrict__ out)
{
    __shared__ unsigned int rv2_s[64][64];    // (px0,px1) fp16 pairs, 16KB
    __shared__ unsigned int act2_s[64][64];   // 16KB
    __shared__ __half w1s[64][64];            // [c_in][k_out] 8KB
    __shared__ __half w2s[64][64];            // [j_in][c_out] 8KB
    __shared__ float  dwks[576];
    __shared__ __half2 pb1h[32], pb2h[32];
    __shared__ float  rdwbs[64], lss[64];
    int t = threadIdx.x;
    for (int i = t; i < 4096; i += 512) {
        w1s[i>>6][i&63] = __float2half(pw1T[i]);
        w2s[i>>6][i&63] = __float2half(pw2T[i]);
    }
    for (int i = t; i < 576; i += 512) dwks[i] = rdwk[i];
    if (t < 64) { rdwbs[t]=rdwb[t]; lss[t]=ls[t]; }
    if (t < 32) {
        pb1h[t] = __floats2half2_rn(pb1[2*t], pb1[2*t+1]);
        pb2h[t] = __floats2half2_rn(pb2[2*t], pb2[2*t+1]);
    }

    int l  = t & 63;                 // px-pair index: px0 = 2l, px1 = 2l+1
    int g  = t >> 6;                 // 0..7
    int c0 = g << 3;                 // 8-channel group
    int row = blockIdx.x;            // 0..1023
    int b = row >> 7, y = row & 127;
    int base = b * Cn * HWn + y * Wn;
    int px0 = l << 1;

    int   yo[3] = { y > 0 ? -Wn : 0, 0, y < Hn-1 ? Wn : 0 };
    float my[3] = { y > 0 ? 1.f : 0.f, 1.f, y < Hn-1 ? 1.f : 0.f };
    float wl = l > 0  ? 1.f : 0.f;   // px0's left tap validity
    float wr = l < 63 ? 1.f : 0.f;   // px1's right tap validity
    int loff = l > 0 ? -1 : 0;       // clamp to avoid OOB-before-buffer read
    __syncthreads();

    // ---- phase 1: depthwise conv, 2 px x 8 ch ----
#pragma unroll
    for (int cc = 0; cc < 8; cc++) {
        int c = c0 + cc;
        int cb = base + c*HWn + px0;
        float rv0 = rdwbs[c], rv1 = rdwbs[c];
#pragma unroll
        for (int r = 0; r < 3; r++) {
            const __half* __restrict__ rp = outp + cb + yo[r];
            unsigned int cu = *reinterpret_cast<const unsigned int*>(rp);
            float2 ct = __half22float2(*(__half2*)&cu);
            float lf = __half2float(rp[loff]);     // masked by wl
            float rt = __half2float(rp[2]);        // masked by wr (stays in outp buffer)
            float k0 = dwks[c*9 + r*3 + 0] * my[r];
            float k1 = dwks[c*9 + r*3 + 1] * my[r];
            float k2 = dwks[c*9 + r*3 + 2] * my[r];
            rv0 += k0*(wl*lf) + k1*ct.x + k2*ct.y;
            rv1 += k0*ct.x + k1*ct.y + k2*(wr*rt);
        }
        __half2 hv = __floats2half2_rn(rv0, rv1);
        rv2_s[c][l] = *(unsigned int*)&hv;
    }
    __syncthreads();

    // ---- phase 2: act = lrelu(pb1 + pw1 @ rv), b128 broadcast weights ----
    __half2 accA[4], accB[4];
#pragma unroll
    for (int q = 0; q < 4; q++) { accA[q] = pb1h[(c0 >> 1) + q]; accB[q] = accA[q]; }
#pragma unroll 8
    for (int c = 0; c < 64; c++) {
        unsigned int rvu = rv2_s[c][l];
        __half2 rvp = *(__half2*)&rvu;
        __half2 r0 = __half2half2(__low2half(rvp));
        __half2 r1 = __half2half2(__high2half(rvp));
        uint4 wq = *reinterpret_cast<const uint4*>(&w1s[c][c0]);
        __half2 w01 = *(__half2*)&wq.x, w23 = *(__half2*)&wq.y;
        __half2 w45 = *(__half2*)&wq.z, w67 = *(__half2*)&wq.w;
        accA[0] = __hfma2(w01, r0, accA[0]); accB[0] = __hfma2(w01, r1, accB[0]);
        accA[1] = __hfma2(w23, r0, accA[1]); accB[1] = __hfma2(w23, r1, accB[1]);
        accA[2] = __hfma2(w45, r0, accA[2]); accB[2] = __hfma2(w45, r1, accB[2]);
        accA[3] = __hfma2(w67, r0, accA[3]); accB[3] = __hfma2(w67, r1, accB[3]);
    }
#pragma unroll
    for (int q = 0; q < 4; q++) {
        float2 a0 = __half22float2(accA[q]);
        float2 a1 = __half22float2(accB[q]);
        float e0 = a0.x > 0.f ? a0.x : 0.2f*a0.x;   // k=c0+2q, px0
        float e1 = a0.y > 0.f ? a0.y : 0.2f*a0.y;   // k=c0+2q+1, px0
        float e2 = a1.x > 0.f ? a1.x : 0.2f*a1.x;   // k=c0+2q, px1
        float e3 = a1.y > 0.f ? a1.y : 0.2f*a1.y;   // k=c0+2q+1, px1
        __half2 p0 = __floats2half2_rn(e0, e2);     // (px0,px1) for k=c0+2q
        __half2 p1 = __floats2half2_rn(e1, e3);     // (px0,px1) for k=c0+2q+1
        act2_s[c0 + 2*q][l]     = *(unsigned int*)&p0;
        act2_s[c0 + 2*q + 1][l] = *(unsigned int*)&p1;
    }
    __syncthreads();

    // ---- phase 3: out = outp + ls * (pb2 + pw2 @ act) ----
#pragma unroll
    for (int q = 0; q < 4; q++) { accA[q] = pb2h[(c0 >> 1) + q]; accB[q] = accA[q]; }
#pragma unroll 8
    for (int j = 0; j < 64; j++) {
        unsigned int au = act2_s[j][l];
        __half2 ap = *(__half2*)&au;
        __half2 a0 = __half2half2(__low2half(ap));
        __half2 a1 = __half2half2(__high2half(ap));
        uint4 wq = *reinterpret_cast<const uint4*>(&w2s[j][c0]);
        __half2 w01 = *(__half2*)&wq.x, w23 = *(__half2*)&wq.y;
        __half2 w45 = *(__half2*)&wq.z, w67 = *(__half2*)&wq.w;
        accA[0] = __hfma2(w01, a0, accA[0]); accB[0] = __hfma2(w01, a1, accB[0]);
        accA[1] = __hfma2(w23, a0, accA[1]); accB[1] = __hfma2(w23, a1, accB[1]);
        accA[2] = __hfma2(w45, a0, accA[2]); accB[2] = __hfma2(w45, a1, accB[2]);
        accA[3] = __hfma2(w67, a0, accA[3]); accB[3] = __hfma2(w67, a1, accB[3]);
    }
#pragma unroll
    for (int q = 0; q < 4; q++) {
        float2 a0 = __half22float2(accA[q]);    // px0: ch c0+2q, c0+2q+1
        float2 a1 = __half22float2(accB[q]);    // px1
        int ca = c0 + 2*q, cb2 = ca + 1;
        int ba = base + ca*HWn + px0;
        int bb = base + cb2*HWn + px0;
        unsigned int oua = *reinterpret_cast<const unsigned int*>(outp + ba);
        unsigned int oub = *reinterpret_cast<const unsigned int*>(outp + bb);
        float2 oa = __half22float2(*(__half2*)&oua);
        float2 ob = __half22float2(*(__half2*)&oub);
        float la = lss[ca], lb = lss[cb2];
        *reinterpret_cast<float2*>(out + ba) = make_float2(oa.x + la*a0.x, oa.y + la*a1.x);
        *reinterpret_cast<float2*>(out + bb) = make_float2(ob.x + lb*a0.y, ob.y + lb*a1.y);
    }
}

extern "C" void kernel_launch(void* const* d_in, const int* in_sizes, int n_in,
                              void* d_out, int out_size, void* d_ws, size_t ws_size,
                              hipStream_t stream)
{
    (void)in_sizes; (void)n_in; (void)out_size; (void)ws_size;
    const float* force   = (const float*)d_in[0];
    const float* style   = (const float*)d_in[1];
    const float* illum   = (const float*)d_in[2];
    const float* h_w1    = (const float*)d_in[3];
    const float* h_b1    = (const float*)d_in[4];
    const float* h_w2    = (const float*)d_in[5];
    const float* h_b2    = (const float*)d_in[6];
    const float* h_w3    = (const float*)d_in[7];
    const float* h_b3    = (const float*)d_in[8];
    const float* dw_k    = (const float*)d_in[9];
    const float* pw_w    = (const float*)d_in[10];
    const float* r_dw_k  = (const float*)d_in[11];
    const float* r_dw_b  = (const float*)d_in[12];
    const float* r_pw1_w = (const float*)d_in[13];
    const float* r_pw1_b = (const float*)d_in[14];
    const float* r_pw2_w = (const float*)d_in[15];
    const float* r_pw2_b = (const float*)d_in[16];
    const float* lscale  = (const float*)d_in[17];

    float* out  = (float*)d_out;              // holds GB (half2) until refine overwrites
    float* Xf32 = out + (size_t)NTOT;         // final x fp32
    float* Vf32 = out + 2*(size_t)NTOT;       // final v fp32
    __half2* GB = (__half2*)out;

    char* w = (char*)d_ws;
    __half2* AB = (__half2*)w; w += (size_t)NTOT*4;
    __half*  F  = (__half*)w;  w += (size_t)NTOT*2;
    __half*  XA = (__half*)w;  w += (size_t)NTOT*2;
    __half*  XB = (__half*)w;  w += (size_t)NTOT*2;
    __half*  Vh = (__half*)w;  w += (size_t)NTOT*2;
    float* w1T  = (float*)w;
    float* c1   = w1T + 2048;
    float* pwT  = c1 + 32;
    float* pw1T = pwT + 4096;
    float* pw2T = pw1T + 4096;
    float* mu   = pw2T + 4096;
    float* rs   = mu + 512;
    __half* outp = (__half*)AB;               // AB dead after last osc step

    fuseF0<<<NTOT/1024, 256, 0, stream>>>((const float4*)force, (const float4*)illum,
                                          F, XA, Vh);
    prep<<<1, 256, 0, stream>>>(style, h_w1, h_b1, pw_w, r_pw1_w, r_pw2_w,
                                w1T, c1, pwT, pw1T, pw2T);
    hyper2<<<dim3(NPIX/256, 2), 256, 0, stream>>>(F, w1T, c1, h_w2, h_b2, h_w3, h_b3,
                                                  AB, GB);
    for (int s = 1; s <= 8; s++) {
        const __half* xin = (s & 1) ? XA : XB;
        __half*      xout = (s & 1) ? XB : XA;
        osc_step<false><<<dim3(NPIX/256, 4), 256, 0, stream>>>(xin, xout, Vh, F, AB,
                                                               dw_k, pwT, nullptr, nullptr);
    }
    // step 9 (odd): reads XA, writes fp32 x,v directly to d_out
    osc_step<true><<<dim3(NPIX/256, 4), 256, 0, stream>>>(XA, XB, Vh, F, AB,
                                                          dw_k, pwT, Xf32, Vf32);
    inorm_stats<<<Bn*Cn, 256, 0, stream>>>(F, Xf32, mu, rs);
    modulate<<<NTOT/1024, 256, 0, stream>>>(F, (const float4*)Xf32,
                                            (const uint4*)GB, mu, rs, outp);
    refine<<<NPIX/128, 512, 0, stream>>>(outp, r_dw_k, r_dw_b, pw1T, r_pw1_b,
                                         pw2T, r_pw2_b, lscale, out);
}

// Round 12
// 495.104 us; speedup vs baseline: 1.3281x; 1.0275x over previous
//
#include <hip/hip_runtime.h>
#include <hip/hip_fp16.h>

#define Hn 128
#define Wn 128
#define HWn 16384
#define Cn 64
#define Bn 8
#define NTOT (Bn*Cn*HWn)   /* 8388608 */
#define NPIX (Bn*HWn)      /* 131072  */
#define DTc 0.3f
#define EPSc 1e-5f

__device__ __forceinline__ float sigm(float t){ return 1.0f/(1.0f+__expf(-t)); }

// ---------------- F = force + 0.2*illum (fp16) + fused oscillator step 0 ----------------
// x0=v0=0  =>  accel0 = F, v1 = 0.3*F, x1 = 0.09*F
__global__ void fuseF0(const float4* __restrict__ force, const float4* __restrict__ illum,
                       __half* __restrict__ F, __half* __restrict__ XA, __half* __restrict__ V)
{
    int i = blockIdx.x * blockDim.x + threadIdx.x;      // NTOT/4 threads
    float4 f = force[i], il = illum[i];
    float a0 = f.x + 0.2f*il.x, a1 = f.y + 0.2f*il.y;
    float a2 = f.z + 0.2f*il.z, a3 = f.w + 0.2f*il.w;
    uint2 pf, px, pv;
    __half2 h;
    h = __floats2half2_rn(a0, a1);            pf.x = *(unsigned int*)&h;
    h = __floats2half2_rn(a2, a3);            pf.y = *(unsigned int*)&h;
    h = __floats2half2_rn(0.09f*a0, 0.09f*a1); px.x = *(unsigned int*)&h;
    h = __floats2half2_rn(0.09f*a2, 0.09f*a3); px.y = *(unsigned int*)&h;
    h = __floats2half2_rn(0.3f*a0, 0.3f*a1);   pv.x = *(unsigned int*)&h;
    h = __floats2half2_rn(0.3f*a2, 0.3f*a3);   pv.y = *(unsigned int*)&h;
    *reinterpret_cast<uint2*>(F  + 4*(size_t)i) = pf;
    *reinterpret_cast<uint2*>(XA + 4*(size_t)i) = px;
    *reinterpret_cast<uint2*>(V  + 4*(size_t)i) = pv;
}

// ---------------- prep: style constant + weight transposes + packed w3 pairs ------------
__global__ void prep(const float* __restrict__ style, const float* __restrict__ w1,
                     const float* __restrict__ b1, const float* __restrict__ pw,
                     const float* __restrict__ pw1, const float* __restrict__ pw2,
                     const float* __restrict__ w3, const float* __restrict__ b3,
                     float* __restrict__ w1T, float* __restrict__ c1,
                     float* __restrict__ pwT, float* __restrict__ pw1T,
                     float* __restrict__ pw2T,
                     __half2* __restrict__ w3abP, __half2* __restrict__ w3gbP,
                     __half2* __restrict__ b3abP, __half2* __restrict__ b3gbP)
{
    int t = threadIdx.x;
    if (t < 32) {
        float s = b1[t];
        for (int k = 0; k < 64; k++) s += w1[t*128 + 64 + k] * style[k];
        c1[t] = s;
    }
    for (int i = t; i < 2048; i += 256) { int c = i >> 5, j = i & 31; w1T[i] = w1[j*128 + c]; }
    for (int i = t; i < 4096; i += 256) {
        int c = i >> 6, k = i & 63;
        pwT[i]  = pw[k*64 + c];
        pw1T[i] = pw1[k*64 + c];
        pw2T[i] = pw2[k*64 + c];
    }
    // packed w3 output-pairs: (j, j+64) -> (omega, zeta); (j+128, j+192) -> (gamma, beta)
    for (int i = t; i < 2048; i += 256) {
        int j = i >> 5, k = i & 31;
        w3abP[i] = __floats2half2_rn(w3[j*32 + k],         w3[(64 + j)*32 + k]);
        w3gbP[i] = __floats2half2_rn(w3[(128 + j)*32 + k], w3[(192 + j)*32 + k]);
    }
    if (t < 64) {
        b3abP[t] = __floats2half2_rn(b3[t],       b3[64 + t]);
        b3gbP[t] = __floats2half2_rn(b3[128 + t], b3[192 + t]);
    }
}

// ---------------- hyper encoder, merged: one pass -> AB and GB ----------------
__global__ void hyperM(const __half* __restrict__ F,
                       const float* __restrict__ w1T, const float* __restrict__ c1,
                       const float* __restrict__ w2, const float* __restrict__ b2,
                       const __half2* __restrict__ w3abP, const __half2* __restrict__ w3gbP,
                       const __half2* __restrict__ b3abP, const __half2* __restrict__ b3gbP,
                       __half2* __restrict__ AB, __half2* __restrict__ GB)
{
    int p = blockIdx.x * blockDim.x + threadIdx.x;
    int b  = p >> 14;
    int sp = p & (HWn - 1);
    int base = b * Cn * HWn + sp;

    float u1[32];
#pragma unroll
    for (int j = 0; j < 32; j++) u1[j] = c1[j];
#pragma unroll 4
    for (int c = 0; c < 64; c++) {
        float fc = __half2float(F[base + c*HWn]);
        const float* __restrict__ wr = w1T + c*32;
#pragma unroll
        for (int j = 0; j < 32; j++) u1[j] += wr[j] * fc;
    }
#pragma unroll
    for (int j = 0; j < 32; j++) { float v = u1[j]; u1[j] = v > 0.f ? v : 0.2f*v; }

    float u2[32];
#pragma unroll
    for (int i = 0; i < 32; i++) {
        float s = b2[i];
#pragma unroll
        for (int j = 0; j < 32; j++) s += w2[i*32 + j] * u1[j];
        u2[i] = s > 0.f ? s : 0.2f*s;
    }
    __half2 u2b[32];
#pragma unroll
    for (int i = 0; i < 32; i++) u2b[i] = __half2half2(__float2half(u2[i]));

#pragma unroll 2
    for (int j = 0; j < 64; j++) {
        __half2 aab = b3abP[j];
        __half2 agb = b3gbP[j];
        const __half2* __restrict__ wa = w3abP + j*32;
        const __half2* __restrict__ wg = w3gbP + j*32;
#pragma unroll
        for (int i = 0; i < 32; i++) {
            aab = __hfma2(wa[i], u2b[i], aab);
            agb = __hfma2(wg[i], u2b[i], agb);
        }
        float2 tab = __half22float2(aab);
        float om = 2.0f * sigm(tab.x);
        float ze = sigm(tab.y);
        AB[base + j*HWn] = __floats2half2_rn(2.0f * ze * om, om * om);
        float2 tgb = __half22float2(agb);
        GB[base + j*HWn] = __floats2half2_rn(2.0f * sigm(tgb.x), tanhf(tgb.y));
    }
}

// ---------------- one symplectic-Euler oscillator step (R8 structure + XCD swizzle) -----
// 1D grid of 2048: xcd = wid&7 owns contiguous 1/8 of pixel space; the 4 channel-group
// blocks of one pixel-chunk are 8 apart in dispatch -> same XCD L2 shares the X rows.
template <bool LAST>
__global__ void osc_step(const __half* __restrict__ Xin, __half* __restrict__ Xout,
                         __half* __restrict__ V, const __half* __restrict__ F,
                         const __half2* __restrict__ AB,
                         const float* __restrict__ dwk, const float* __restrict__ pwT,
                         float* __restrict__ Xf, float* __restrict__ Vf)
{
    int wid  = blockIdx.x;
    int slot = wid >> 3;
    int pc   = ((wid & 7) << 6) + (slot >> 2);   // pixel-chunk 0..511
    int c0   = (slot & 3) << 4;                  // channel group start
    int p = (pc << 8) + threadIdx.x;
    int b  = p >> 14;
    int sp = p & (HWn - 1);
    int y = sp >> 7, x = sp & 127;
    int base = b * Cn * HWn + sp;

    // pointwise coupling: acc[kk] = sum_c pw[c0+kk][c] * x[c]
    float acc[16];
#pragma unroll
    for (int k = 0; k < 16; k++) acc[k] = 0.f;
#pragma unroll 4
    for (int c = 0; c < 64; c++) {
        float xc = __half2float(Xin[base + c*HWn]);
        const float* __restrict__ wr = pwT + c*64 + c0;
#pragma unroll
        for (int k = 0; k < 16; k++) acc[k] += wr[k] * xc;
    }

    // 3x3 tap masks/offsets (zero 'SAME' padding)
    int   yo[3] = { y > 0 ? -Wn : 0, 0, y < Hn-1 ? Wn : 0 };
    int   xo[3] = { x > 0 ? -1  : 0, 0, x < Wn-1 ? 1  : 0 };
    float my[3] = { y > 0 ? 1.f : 0.f, 1.f, y < Hn-1 ? 1.f : 0.f };
    float mx[3] = { x > 0 ? 1.f : 0.f, 1.f, x < Wn-1 ? 1.f : 0.f };
    float mm[9]; int oo[9];
#pragma unroll
    for (int dy = 0; dy < 3; dy++)
#pragma unroll
        for (int dx = 0; dx < 3; dx++) { mm[dy*3+dx] = my[dy]*mx[dx]; oo[dy*3+dx] = yo[dy]+xo[dx]; }

#pragma unroll
    for (int cc = 0; cc < 16; cc++) {
        int c = c0 + cc;
        int cb = base + c*HWn;
        float tv[9];
#pragma unroll
        for (int t = 0; t < 9; t++) tv[t] = __half2float(Xin[cb + oo[t]]);
        float dws = 0.f;
#pragma unroll
        for (int t = 0; t < 9; t++) dws += (dwk[c*9 + t] * mm[t]) * tv[t];
        float xc = tv[4];
        float2 ab = __half22float2(AB[cb]);
        float vv = __half2float(V[cb]);
        float accel = __half2float(F[cb]) + acc[cc] + dws - ab.x * vv - ab.y * xc;
        vv += accel * DTc;
        float xn = xc + vv * DTc;
        if constexpr (!LAST) {
            V[cb] = __float2half(vv);
            Xout[cb] = __float2half(xn);
        } else {
            Xf[cb] = xn;
            Vf[cb] = vv;
        }
    }
}

// ---------------- instance norm stats ----------------
__global__ void inorm_stats(const __half* __restrict__ F, const float* __restrict__ X,
                            float* __restrict__ mu, float* __restrict__ rs)
{
    int bc = blockIdx.x;             // 0..511
    int base = bc * HWn;
    const __half2* __restrict__ F2 = (const __half2*)(F + base);
    const float4*  __restrict__ X4 = (const float4*)(X + base);
    float s = 0.f, s2 = 0.f;
    for (int i = threadIdx.x; i < HWn/4; i += blockDim.x) {
        float4 xv = X4[i];
        float2 f0 = __half22float2(F2[2*i]);
        float2 f1 = __half22float2(F2[2*i+1]);
        float v0 = f0.x + xv.x, v1 = f0.y + xv.y, v2 = f1.x + xv.z, v3 = f1.y + xv.w;
        s += (v0 + v1) + (v2 + v3);
        s2 += (v0*v0 + v1*v1) + (v2*v2 + v3*v3);
    }
#pragma unroll
    for (int o = 32; o > 0; o >>= 1) { s += __shfl_down(s, o); s2 += __shfl_down(s2, o); }
    __shared__ float sh[16];
    int w = threadIdx.x >> 6, l = threadIdx.x & 63;
    if (l == 0) { sh[w] = s; sh[8 + w] = s2; }
    __syncthreads();
    if (threadIdx.x == 0) {
        float S = 0.f, S2 = 0.f;
        for (int i = 0; i < 4; i++) { S += sh[i]; S2 += sh[8 + i]; }
        float m = S / (float)HWn;
        float var = S2 / (float)HWn - m*m;
        mu[bc] = m;
        rs[bc] = rsqrtf(var + EPSc);
    }
}

// ---------------- instance norm apply + style modulation -> out_pre (fp16) ----------------
__global__ void modulate(const __half* __restrict__ F, const float4* __restrict__ X4,
                         const uint4* __restrict__ GBu, const float* __restrict__ mu,
                         const float* __restrict__ rs, __half* __restrict__ outp)
{
    int e4 = blockIdx.x * blockDim.x + threadIdx.x;   // NTOT/4 threads
    int bc = e4 >> 12;                                // (e4*4) >> 14
    float m = mu[bc], r = rs[bc];
    uint2 fu = *reinterpret_cast<const uint2*>(F + 4*(size_t)e4);
    float2 f0 = __half22float2(*(__half2*)&fu.x);
    float2 f1 = __half22float2(*(__half2*)&fu.y);
    float4 xv = X4[e4];
    uint4 gb = GBu[e4];
    float2 g0 = __half22float2(*(__half2*)&gb.x);
    float2 g1 = __half22float2(*(__half2*)&gb.y);
    float2 g2 = __half22float2(*(__half2*)&gb.z);
    float2 g3 = __half22float2(*(__half2*)&gb.w);
    float o0 = g0.x * ((f0.x + xv.x - m) * r) + g0.y;
    float o1 = g1.x * ((f0.y + xv.y - m) * r) + g1.y;
    float o2 = g2.x * ((f1.x + xv.z - m) * r) + g2.y;
    float o3 = g3.x * ((f1.y + xv.w - m) * r) + g3.y;
    __half2 h01 = __floats2half2_rn(o0, o1);
    __half2 h23 = __floats2half2_rn(o2, o3);
    uint2 pack; pack.x = *(unsigned int*)&h01; pack.y = *(unsigned int*)&h23;
    *reinterpret_cast<uint2*>(outp + 4*(size_t)e4) = pack;
}

// ---------------- refine v3: one row/block, 2 px x 8 ch per thread, b128 weight reads ----
__global__ __launch_bounds__(512)
void refine(const __half* __restrict__ outp,
            const float* __restrict__ rdwk, const float* __restrict__ rdwb,
            const float* __restrict__ pw1T, const float* __restrict__ pb1,
            const float* __restrict__ pw2T, const float* __restrict__ pb2,
            const float* __restrict__ ls, float* __restrict__ out)
{
    __shared__ unsigned int rv2_s[64][64];    // (px0,px1) fp16 pairs, 16KB
    __shared__ unsigned int act2_s[64][64];   // 16KB
    __shared__ __half w1s[64][64];            // [c_in][k_out] 8KB
    __shared__ __half w2s[64][64];            // [j_in][c_out] 8KB
    __shared__ float  dwks[576];
    __shared__ __half2 pb1h[32], pb2h[32];
    __shared__ float  rdwbs[64], lss[64];
    int t = threadIdx.x;
    for (int i = t; i < 4096; i += 512) {
        w1s[i>>6][i&63] = __float2half(pw1T[i]);
        w2s[i>>6][i&63] = __float2half(pw2T[i]);
    }
    for (int i = t; i < 576; i += 512) dwks[i] = rdwk[i];
    if (t < 64) { rdwbs[t]=rdwb[t]; lss[t]=ls[t]; }
    if (t < 32) {
        pb1h[t] = __floats2half2_rn(pb1[2*t], pb1[2*t+1]);
        pb2h[t] = __floats2half2_rn(pb2[2*t], pb2[2*t+1]);
    }

    int l  = t & 63;                 // px-pair index: px0 = 2l, px1 = 2l+1
    int g  = t >> 6;                 // 0..7
    int c0 = g << 3;                 // 8-channel group
    int row = blockIdx.x;            // 0..1023
    int b = row >> 7, y = row & 127;
    int base = b * Cn * HWn + y * Wn;
    int px0 = l << 1;

    int   yo[3] = { y > 0 ? -Wn : 0, 0, y < Hn-1 ? Wn : 0 };
    float my[3] = { y > 0 ? 1.f : 0.f, 1.f, y < Hn-1 ? 1.f : 0.f };
    float wl = l > 0  ? 1.f : 0.f;
    float wr = l < 63 ? 1.f : 0.f;
    int loff = l > 0 ? -1 : 0;
    __syncthreads();

    // ---- phase 1: depthwise conv, 2 px x 8 ch ----
#pragma unroll
    for (int cc = 0; cc < 8; cc++) {
        int c = c0 + cc;
        int cb = base + c*HWn + px0;
        float rv0 = rdwbs[c], rv1 = rdwbs[c];
#pragma unroll
        for (int r = 0; r < 3; r++) {
            const __half* __restrict__ rp = outp + cb + yo[r];
            unsigned int cu = *reinterpret_cast<const unsigned int*>(rp);
            float2 ct = __half22float2(*(__half2*)&cu);
            float lf = __half2float(rp[loff]);
            float rt = __half2float(rp[2]);
            float k0 = dwks[c*9 + r*3 + 0] * my[r];
            float k1 = dwks[c*9 + r*3 + 1] * my[r];
            float k2 = dwks[c*9 + r*3 + 2] * my[r];
            rv0 += k0*(wl*lf) + k1*ct.x + k2*ct.y;
            rv1 += k0*ct.x + k1*ct.y + k2*(wr*rt);
        }
        __half2 hv = __floats2half2_rn(rv0, rv1);
        rv2_s[c][l] = *(unsigned int*)&hv;
    }
    __syncthreads();

    // ---- phase 2: act = lrelu(pb1 + pw1 @ rv), b128 broadcast weights ----
    __half2 accA[4], accB[4];
#pragma unroll
    for (int q = 0; q < 4; q++) { accA[q] = pb1h[(c0 >> 1) + q]; accB[q] = accA[q]; }
#pragma unroll 8
    for (int c = 0; c < 64; c++) {
        unsigned int rvu = rv2_s[c][l];
        __half2 rvp = *(__half2*)&rvu;
        __half2 r0 = __half2half2(__low2half(rvp));
        __half2 r1 = __half2half2(__high2half(rvp));
        uint4 wq = *reinterpret_cast<const uint4*>(&w1s[c][c0]);
        __half2 w01 = *(__half2*)&wq.x, w23 = *(__half2*)&wq.y;
        __half2 w45 = *(__half2*)&wq.z, w67 = *(__half2*)&wq.w;
        accA[0] = __hfma2(w01, r0, accA[0]); accB[0] = __hfma2(w01, r1, accB[0]);
        accA[1] = __hfma2(w23, r0, accA[1]); accB[1] = __hfma2(w23, r1, accB[1]);
        accA[2] = __hfma2(w45, r0, accA[2]); accB[2] = __hfma2(w45, r1, accB[2]);
        accA[3] = __hfma2(w67, r0, accA[3]); accB[3] = __hfma2(w67, r1, accB[3]);
    }
#pragma unroll
    for (int q = 0; q < 4; q++) {
        float2 a0 = __half22float2(accA[q]);
        float2 a1 = __half22float2(accB[q]);
        float e0 = a0.x > 0.f ? a0.x : 0.2f*a0.x;
        float e1 = a0.y > 0.f ? a0.y : 0.2f*a0.y;
        float e2 = a1.x > 0.f ? a1.x : 0.2f*a1.x;
        float e3 = a1.y > 0.f ? a1.y : 0.2f*a1.y;
        __half2 p0 = __floats2half2_rn(e0, e2);
        __half2 p1 = __floats2half2_rn(e1, e3);
        act2_s[c0 + 2*q][l]     = *(unsigned int*)&p0;
        act2_s[c0 + 2*q + 1][l] = *(unsigned int*)&p1;
    }
    __syncthreads();

    // ---- phase 3: out = outp + ls * (pb2 + pw2 @ act) ----
#pragma unroll
    for (int q = 0; q < 4; q++) { accA[q] = pb2h[(c0 >> 1) + q]; accB[q] = accA[q]; }
#pragma unroll 8
    for (int j = 0; j < 64; j++) {
        unsigned int au = act2_s[j][l];
        __half2 ap = *(__half2*)&au;
        __half2 a0 = __half2half2(__low2half(ap));
        __half2 a1 = __half2half2(__high2half(ap));
        uint4 wq = *reinterpret_cast<const uint4*>(&w2s[j][c0]);
        __half2 w01 = *(__half2*)&wq.x, w23 = *(__half2*)&wq.y;
        __half2 w45 = *(__half2*)&wq.z, w67 = *(__half2*)&wq.w;
        accA[0] = __hfma2(w01, a0, accA[0]); accB[0] = __hfma2(w01, a1, accB[0]);
        accA[1] = __hfma2(w23, a0, accA[1]); accB[1] = __hfma2(w23, a1, accB[1]);
        accA[2] = __hfma2(w45, a0, accA[2]); accB[2] = __hfma2(w45, a1, accB[2]);
        accA[3] = __hfma2(w67, a0, accA[3]); accB[3] = __hfma2(w67, a1, accB[3]);
    }
#pragma unroll
    for (int q = 0; q < 4; q++) {
        float2 a0 = __half22float2(accA[q]);
        float2 a1 = __half22float2(accB[q]);
        int ca = c0 + 2*q, cb2 = ca + 1;
        int ba = base + ca*HWn + px0;
        int bb = base + cb2*HWn + px0;
        unsigned int oua = *reinterpret_cast<const unsigned int*>(outp + ba);
        unsigned int oub = *reinterpret_cast<const unsigned int*>(outp + bb);
        float2 oa = __half22float2(*(__half2*)&oua);
        float2 ob = __half22float2(*(__half2*)&oub);
        float la = lss[ca], lb = lss[cb2];
        *reinterpret_cast<float2*>(out + ba) = make_float2(oa.x + la*a0.x, oa.y + la*a1.x);
        *reinterpret_cast<float2*>(out + bb) = make_float2(ob.x + lb*a0.y, ob.y + lb*a1.y);
    }
}

extern "C" void kernel_launch(void* const* d_in, const int* in_sizes, int n_in,
                              void* d_out, int out_size, void* d_ws, size_t ws_size,
                              hipStream_t stream)
{
    (void)in_sizes; (void)n_in; (void)out_size; (void)ws_size;
    const float* force   = (const float*)d_in[0];
    const float* style   = (const float*)d_in[1];
    const float* illum   = (const float*)d_in[2];
    const float* h_w1    = (const float*)d_in[3];
    const float* h_b1    = (const float*)d_in[4];
    const float* h_w2    = (const float*)d_in[5];
    const float* h_b2    = (const float*)d_in[6];
    const float* h_w3    = (const float*)d_in[7];
    const float* h_b3    = (const float*)d_in[8];
    const float* dw_k    = (const float*)d_in[9];
    const float* pw_w    = (const float*)d_in[10];
    const float* r_dw_k  = (const float*)d_in[11];
    const float* r_dw_b  = (const float*)d_in[12];
    const float* r_pw1_w = (const float*)d_in[13];
    const float* r_pw1_b = (const float*)d_in[14];
    const float* r_pw2_w = (const float*)d_in[15];
    const float* r_pw2_b = (const float*)d_in[16];
    const float* lscale  = (const float*)d_in[17];

    float* out  = (float*)d_out;              // holds GB (half2) until refine overwrites
    float* Xf32 = out + (size_t)NTOT;         // final x fp32
    float* Vf32 = out + 2*(size_t)NTOT;       // final v fp32
    __half2* GB = (__half2*)out;

    char* w = (char*)d_ws;
    __half2* AB = (__half2*)w; w += (size_t)NTOT*4;
    __half*  F  = (__half*)w;  w += (size_t)NTOT*2;
    __half*  XA = (__half*)w;  w += (size_t)NTOT*2;
    __half*  XB = (__half*)w;  w += (size_t)NTOT*2;
    __half*  Vh = (__half*)w;  w += (size_t)NTOT*2;
    float* w1T  = (float*)w;
    float* c1   = w1T + 2048;
    float* pwT  = c1 + 32;
    float* pw1T = pwT + 4096;
    float* pw2T = pw1T + 4096;
    float* mu   = pw2T + 4096;
    float* rs   = mu + 512;
    __half2* w3abP = (__half2*)(rs + 512);
    __half2* w3gbP = w3abP + 2048;
    __half2* b3abP = w3gbP + 2048;
    __half2* b3gbP = b3abP + 64;
    __half* outp = (__half*)AB;               // AB dead after last osc step

    fuseF0<<<NTOT/1024, 256, 0, stream>>>((const float4*)force, (const float4*)illum,
                                          F, XA, Vh);
    prep<<<1, 256, 0, stream>>>(style, h_w1, h_b1, pw_w, r_pw1_w, r_pw2_w, h_w3, h_b3,
                                w1T, c1, pwT, pw1T, pw2T, w3abP, w3gbP, b3abP, b3gbP);
    hyperM<<<NPIX/256, 256, 0, stream>>>(F, w1T, c1, h_w2, h_b2,
                                         w3abP, w3gbP, b3abP, b3gbP, AB, GB);
    for (int s = 1; s <= 8; s++) {
        const __half* xin = (s & 1) ? XA : XB;
        __half*      xout = (s & 1) ? XB : XA;
        osc_step<false><<<2048, 256, 0, stream>>>(xin, xout, Vh, F, AB,
                                                  dw_k, pwT, nullptr, nullptr);
    }
    // step 9 (odd): reads XA, writes fp32 x,v directly to d_out
    osc_step<true><<<2048, 256, 0, stream>>>(XA, XB, Vh, F, AB,
                                             dw_k, pwT, Xf32, Vf32);
    inorm_stats<<<Bn*Cn, 256, 0, stream>>>(F, Xf32, mu, rs);
    modulate<<<NTOT/1024, 256, 0, stream>>>(F, (const float4*)Xf32,
                                            (const uint4*)GB, mu, rs, outp);
    refine<<<NPIX/128, 512, 0, stream>>>(outp, r_dw_k, r_dw_b, pw1T, r_pw1_b,
                                         pw2T, r_pw2_b, lscale, out);
}